// Round 10
// baseline (176.922 us; speedup 1.0000x reference)
//
#include <hip/hip_runtime.h>
#include <hip/hip_bf16.h>

#define B_  16384
#define I_  512
#define H1_ 256
#define H2_ 128
#define E_  8
#define T_  2

typedef __attribute__((ext_vector_type(8))) short short8;
typedef __attribute__((ext_vector_type(4))) float float4_t;

__device__ inline unsigned short f2bf(float f) {
    union { float f; unsigned u; } v; v.f = f;
    unsigned r = v.u + 0x7FFFu + ((v.u >> 16) & 1u);
    return (unsigned short)(r >> 16);
}

// async global->LDS, 16B per lane. LDS dest = wave-uniform base + lane*16.
__device__ inline void async_copy16(const unsigned short* g, unsigned short* l) {
    __builtin_amdgcn_global_load_lds(
        (const __attribute__((address_space(1))) void*)g,
        (__attribute__((address_space(3))) void*)l,
        16, 0, 0);
}

// ================= prep + gates megakernel (one dispatch) =================
// VERBATIM r9 (verified): 64-row gates blocks, float4 Wg staging, in-wave softmax.
__global__ void prep_gates_kernel(const float* __restrict__ x,
                                  unsigned short* __restrict__ xb,
                                  const float* __restrict__ W1,
                                  unsigned short* __restrict__ w1t,
                                  const float* __restrict__ W2,
                                  unsigned short* __restrict__ w2t,
                                  const float* __restrict__ Wg,
                                  const float* __restrict__ bg,
                                  float* __restrict__ gates) {
    __shared__ __align__(16) char smem[16 * 520 * 2 + 4 * 16 * 16 * 4];  // 20.6 KB
    int bid = blockIdx.x;
    int t = threadIdx.x;

    if (bid < 256) {
        unsigned short* wgtL = (unsigned short*)smem;          // [16][520] padded
#pragma unroll
        for (int j = 0; j < 8; ++j) {
            int idx4 = j * 256 + t;                 // 0..2047 float4s of Wg
            float4_t wv = ((const float4_t*)Wg)[idx4];
            int e0   = (idx4 & 1) * 4;
            int i    = (idx4 >> 1) & 511;
            int task = idx4 >> 10;
#pragma unroll
            for (int c = 0; c < 4; ++c)
                wgtL[(task * 8 + e0 + c) * 520 + i] = f2bf(wv[c]);
        }
        __syncthreads();

        int w = t >> 6, lane = t & 63;
        int col = lane & 15, quad = lane >> 4;
        int row = bid * 64 + w * 16 + col;          // this wave's A-row
        const float* xr = x + (size_t)row * I_ + quad * 8;
        unsigned short* xw = xb + (size_t)row * I_ + quad * 8;
        const unsigned short* bL = &wgtL[col * 520 + quad * 8];
        float4_t acc = {0.f, 0.f, 0.f, 0.f};
#pragma unroll
        for (int ks = 0; ks < 512; ks += 32) {
            float4_t xa = *(const float4_t*)(xr + ks);
            float4_t xc = *(const float4_t*)(xr + ks + 4);
            short8 a;
            a[0] = (short)f2bf(xa[0]); a[1] = (short)f2bf(xa[1]);
            a[2] = (short)f2bf(xa[2]); a[3] = (short)f2bf(xa[3]);
            a[4] = (short)f2bf(xc[0]); a[5] = (short)f2bf(xc[1]);
            a[6] = (short)f2bf(xc[2]); a[7] = (short)f2bf(xc[3]);
            *(short8*)(xw + ks) = a;
            short8 b = *(const short8*)(bL + ks);
            acc = __builtin_amdgcn_mfma_f32_16x16x32_bf16(a, b, acc, 0, 0, 0);
        }
        // per-lane: acc[p] = logits[local row quad*4+p][te=col]
        float g[4];
#pragma unroll
        for (int p = 0; p < 4; ++p) {
            float v = acc[p] + bg[col];
            float m = v;
            m = fmaxf(m, __shfl_xor(m, 1));
            m = fmaxf(m, __shfl_xor(m, 2));
            m = fmaxf(m, __shfl_xor(m, 4));
            float ev = __expf(v - m);
            float s = ev;
            s += __shfl_xor(s, 1);
            s += __shfl_xor(s, 2);
            s += __shfl_xor(s, 4);
            g[p] = ev / s;
        }
#pragma unroll
        for (int p = 0; p < 4; ++p)
            gates[(size_t)col * B_ + bid * 64 + w * 16 + quad * 4 + p] = g[p];
    } else {
        float (*tile)[33] = (float (*)[33])smem;
        const float* in; unsigned short* outp; int R, C, e, r0, c0;
        if (bid < 1280) {
            int tl = bid - 256;                // 8 e x 16 rblk x 8 cblk = 1024
            e = tl >> 7; int rem = tl & 127;
            R = I_; C = H1_;
            r0 = (rem >> 3) * 32; c0 = (rem & 7) * 32;
            in = W1; outp = w1t;
        } else {
            int tl = bid - 1280;               // 8 e x 8 rblk x 4 cblk = 256
            e = tl >> 5; int rem = tl & 31;
            R = H1_; C = H2_;
            r0 = (rem >> 2) * 32; c0 = (rem & 3) * 32;
            in = W2; outp = w2t;
        }
        const float* inp = in + (size_t)e * R * C;
        unsigned short* op = outp + (size_t)e * R * C;
        int tx = t & 31, ty = t >> 5;          // (32, 8)
#pragma unroll
        for (int j = 0; j < 32; j += 8)
            tile[ty + j][tx] = inp[(size_t)(r0 + ty + j) * C + c0 + tx];
        __syncthreads();
#pragma unroll
        for (int j = 0; j < 32; j += 8)
            op[(size_t)(c0 + ty + j) * R + r0 + tx] = f2bf(tile[tx][ty + j]);
    }
}

// ---------------- layer 1 grouped GEMM: h[e] = relu(xb * w1t[e]^T + b1[e]) bf16 ----------------
// VERBATIM r0 (proven ~49 us): 128x128 tile, 256 threads, 4 blocks/CU.
__global__ void gemm_relu_kernel(const unsigned short* __restrict__ A, size_t aSE,
                                 const unsigned short* __restrict__ Bt, size_t bSE,
                                 const float* __restrict__ bias, int biasSE,
                                 unsigned short* __restrict__ C, size_t cSE,
                                 int K, int lda, int ldb, int ldc) {
    __shared__ unsigned short smem[128 * 136];   // 34 KB: As|Bs, aliased by padded C-tile
    unsigned short* As = smem;                    // 128*64
    unsigned short* Bs = smem + 128 * 64;         // 128*64
    int e = blockIdx.z;
    const unsigned short* Ae = A + (size_t)e * aSE;
    const unsigned short* Be = Bt + (size_t)e * bSE;
    const float* biasE = bias + (size_t)e * biasSE;
    unsigned short* Ce = C + (size_t)e * cSE;
    int m0 = blockIdx.x * 128, n0 = blockIdx.y * 128;
    int t = threadIdx.x, w = t >> 6, lane = t & 63;
    int col = lane & 15, quad = lane >> 4;
    int wm = (w & 1) * 64, wn = (w >> 1) * 64;

    float4_t acc[4][4];
#pragma unroll
    for (int mi = 0; mi < 4; ++mi)
#pragma unroll
        for (int ni = 0; ni < 4; ++ni)
            acc[mi][ni] = (float4_t){0.f, 0.f, 0.f, 0.f};

    int rT = t >> 3;
    int gk = (((t & 7) ^ (rT & 7))) * 8;
    const unsigned short* aG = Ae + (size_t)(m0 + rT) * lda + gk;
    const unsigned short* bG = Be + (size_t)(n0 + rT) * ldb + gk;
    unsigned short* aL = As + (size_t)w * 64 * 8;
    unsigned short* bL = Bs + (size_t)w * 64 * 8;

    for (int k0 = 0; k0 < K; k0 += 64) {
#pragma unroll
        for (int j = 0; j < 4; ++j) {
            async_copy16(aG + (size_t)j * 32 * lda + k0, aL + j * 2048);
            async_copy16(bG + (size_t)j * 32 * ldb + k0, bL + j * 2048);
        }
        __syncthreads();
#pragma unroll
        for (int kk = 0; kk < 64; kk += 32) {
            int q = (kk >> 3) + quad;
            short8 af[4], bf[4];
#pragma unroll
            for (int mi = 0; mi < 4; ++mi) {
                int r = wm + mi * 16 + col;
                af[mi] = *(const short8*)&As[r * 64 + ((q ^ (r & 7)) * 8)];
            }
#pragma unroll
            for (int ni = 0; ni < 4; ++ni) {
                int r = wn + ni * 16 + col;
                bf[ni] = *(const short8*)&Bs[r * 64 + ((q ^ (r & 7)) * 8)];
            }
#pragma unroll
            for (int mi = 0; mi < 4; ++mi)
#pragma unroll
                for (int ni = 0; ni < 4; ++ni)
                    acc[mi][ni] = __builtin_amdgcn_mfma_f32_16x16x32_bf16(af[mi], bf[ni], acc[mi][ni], 0, 0, 0);
        }
        __syncthreads();
    }
    // after final barrier all LDS reads are done -> safe to alias as padded C-tile
    unsigned short* Ct = smem;   // 128 rows x stride 136
#pragma unroll
    for (int ni = 0; ni < 4; ++ni) {
        int c = wn + ni * 16 + col;
        float bv = biasE[n0 + c];
#pragma unroll
        for (int mi = 0; mi < 4; ++mi) {
            int rbase = wm + mi * 16 + quad * 4;
#pragma unroll
            for (int p = 0; p < 4; ++p) {
                float v = acc[mi][ni][p] + bv;
                v = v > 0.f ? v : 0.f;
                Ct[(rbase + p) * 136 + c] = f2bf(v);
            }
        }
    }
    __syncthreads();
    int rr = t >> 4, sl = t & 15;
#pragma unroll
    for (int pass = 0; pass < 8; ++pass) {
        int row = pass * 16 + rr;
        short8 vv = *(const short8*)&Ct[row * 136 + sl * 8];
        *(short8*)&Ce[(size_t)(m0 + row) * ldc + n0 + sl * 8] = vv;
    }
}

// ---------------- fused layer2 + gated combine: split-n ring-3, 52 KB -> 3 blocks/CU ----------------
// 64 rows x full H2 per block, grid 256, 512 threads. Chunk = (expert, k-slice,
// n-half): 64 chunks. A (h rows, 8 KB) staged once per (e,kc) PAIR and read by
// both n-half chunks -> h read ONCE. B slot = 64 n x 64 k (8 KB). LDS = A-ring
// 24 + B-ring 24 + gates 4 = 52 KB -> 3 blocks/CU (24 waves/CU TLP vs r4's 16).
// Race-freedom: B-ring identical to proven r4 (R=3, D=1: writes at cid hit the
// slot read at cid-2, separated by head-barrier(cid-1)). A-ring advances every
// 2 chunks: write of pair p+1 (issued pre-barrier of chunk 2p) hits the slot
// read at chunks 2p-4/2p-3, separated by two head barriers.
// Counted vmcnt (issue order A(p+1),B(cid+1) at even cid; B(cid+1) at odd):
// even cid<=60 -> vmcnt(2); odd cid<=61 -> vmcnt(1); cid=62 -> 1; cid=63 -> 0.
__global__ __launch_bounds__(512, 4)
void fused_l2_combine_kernel(const unsigned short* __restrict__ h,
                             const unsigned short* __restrict__ w2t,
                             const float* __restrict__ b2,
                             const float* __restrict__ gates,
                             float* __restrict__ out) {
    __shared__ __align__(16) unsigned short Aring[3][4096];  // 24 KB: 64 rows x 64 k
    __shared__ __align__(16) unsigned short Bring[3][4096];  // 24 KB: 64 n x 64 k
    __shared__ float gL[16][64];                             //  4 KB

    int b0 = blockIdx.x * 64;
    int t = threadIdx.x, w = t >> 6, lane = t & 63;
    int col = lane & 15, quad = lane >> 4;
    int wm = (w & 1) * 32;          // row offset (2 m-frags of 16)
    int wn = (w >> 1) * 16;         // 16-wide n slice within the active 64-n half

    if (t < 256) {   // stage gates; first read (expert-0 epilogue, cid=7) is past 8 barriers
        int te = t >> 4, r4 = (t & 15) * 4;
        *(float4_t*)&gL[te][r4] = *(const float4_t*)&gates[(size_t)te * B_ + b0 + r4];
    }

    int rowA = t >> 3;                       // 0..63 (dest LDS row; wave w covers rows w*8..w*8+7)
    int csw  = ((t & 7) ^ (rowA & 7)) * 8;   // pre-swizzled source chunk
    int ldsw = w * 512;                      // wave-uniform LDS base (shorts)

    // A chunk pair p = (expert p>>2, k-slice p&3): h rows b0..b0+63, 1 load/thread
    auto stageA = [&](int p) {
        int ee = p >> 2, kc = p & 3;
        const unsigned short* hE = h + ((size_t)ee * B_ + b0 + rowA) * H1_ + kc * 64 + csw;
        async_copy16(hE, &Aring[p % 3][ldsw]);
    };
    // B chunk cid = (ee = cid>>3, kc = (cid>>1)&3, nh = cid&1): 64 n-rows, 1 load/thread
    auto stageB = [&](int cid) {
        int ee = cid >> 3, kc = (cid >> 1) & 3, nh = cid & 1;
        const unsigned short* wE = w2t + ((size_t)(ee * H2_ + nh * 64 + rowA)) * H1_ + kc * 64 + csw;
        async_copy16(wE, &Bring[cid % 3][ldsw]);
    };

    float4_t tw0[2][2], tw1[2][2];   // [mi][n-half]
#pragma unroll
    for (int mi = 0; mi < 2; ++mi)
#pragma unroll
        for (int nh = 0; nh < 2; ++nh) {
            tw0[mi][nh] = (float4_t){0.f, 0.f, 0.f, 0.f};
            tw1[mi][nh] = (float4_t){0.f, 0.f, 0.f, 0.f};
        }

    stageA(0);
    stageB(0);

    float4_t acc[2][2];   // [mi][n-half], reset per expert
    int lastE = -1;
#pragma unroll 1
    for (int cid = 0; cid < 64; ++cid) {
        if ((cid & 1) == 0) {
            if (cid <= 60) {
                stageA((cid >> 1) + 1);
                stageB(cid + 1);
                asm volatile("s_waitcnt vmcnt(2)" ::: "memory");
            } else {            // cid == 62
                stageB(63);
                asm volatile("s_waitcnt vmcnt(1)" ::: "memory");
            }
        } else {
            if (cid <= 61) {
                stageB(cid + 1);
                asm volatile("s_waitcnt vmcnt(1)" ::: "memory");
            } else {            // cid == 63
                asm volatile("s_waitcnt vmcnt(0)" ::: "memory");
            }
        }
        asm volatile("s_barrier" ::: "memory");

        int ee = cid >> 3, nh = cid & 1;
        if (ee != lastE) {
            lastE = ee;
#pragma unroll
            for (int mi = 0; mi < 2; ++mi)
#pragma unroll
                for (int h2 = 0; h2 < 2; ++h2)
                    acc[mi][h2] = (float4_t){0.f, 0.f, 0.f, 0.f};
        }

        const unsigned short* Ac = &Aring[(cid >> 1) % 3][0];
        const unsigned short* Bc = &Bring[cid % 3][0];
        int nl = wn + col;                       // n-row within the 64-n half
#pragma unroll
        for (int kq = 0; kq < 2; ++kq) {
            int q = kq * 4 + quad;
            short8 af[2], bf;
#pragma unroll
            for (int mi = 0; mi < 2; ++mi) {
                int r = wm + mi * 16 + col;
                af[mi] = *(const short8*)&Ac[r * 64 + ((q ^ (r & 7)) << 3)];
            }
            bf = *(const short8*)&Bc[nl * 64 + ((q ^ (nl & 7)) << 3)];
            __builtin_amdgcn_s_setprio(1);
#pragma unroll
            for (int mi = 0; mi < 2; ++mi)
                acc[mi][nh] = __builtin_amdgcn_mfma_f32_16x16x32_bf16(
                    af[mi], bf, acc[mi][nh], 0, 0, 0);
            __builtin_amdgcn_s_setprio(0);
        }

        if ((cid & 7) == 7) {   // expert epilogue: bias + relu + gated accumulate
#pragma unroll
            for (int h2 = 0; h2 < 2; ++h2) {
                float bv = b2[ee * H2_ + h2 * 64 + wn + col];
#pragma unroll
                for (int mi = 0; mi < 2; ++mi) {
#pragma unroll
                    for (int p = 0; p < 4; ++p) {
                        int rloc = wm + mi * 16 + quad * 4 + p;
                        float v = acc[mi][h2][p] + bv;
                        v = v > 0.f ? v : 0.f;
                        tw0[mi][h2][p] += gL[ee][rloc] * v;
                        tw1[mi][h2][p] += gL[8 + ee][rloc] * v;
                    }
                }
            }
        }
    }

    // write out [T][B][H2]: wave covers 32 rows x 16 cols x 2 halves
#pragma unroll
    for (int mi = 0; mi < 2; ++mi) {
#pragma unroll
        for (int h2 = 0; h2 < 2; ++h2) {
            int n = h2 * 64 + wn + col;
#pragma unroll
            for (int p = 0; p < 4; ++p) {
                int r = b0 + wm + mi * 16 + quad * 4 + p;
                out[(size_t)r * H2_ + n] = tw0[mi][h2][p];
                out[(size_t)B_ * H2_ + (size_t)r * H2_ + n] = tw1[mi][h2][p];
            }
        }
    }
}

extern "C" void kernel_launch(void* const* d_in, const int* in_sizes, int n_in,
                              void* d_out, int out_size, void* d_ws, size_t ws_size,
                              hipStream_t stream) {
    const float* x  = (const float*)d_in[0];
    const float* W1 = (const float*)d_in[1];
    const float* b1 = (const float*)d_in[2];
    const float* W2 = (const float*)d_in[3];
    const float* b2 = (const float*)d_in[4];
    const float* Wg = (const float*)d_in[5];
    const float* bg = (const float*)d_in[6];
    float* out = (float*)d_out;

    char* ws = (char*)d_ws;
    unsigned short* xb    = (unsigned short*)(ws);                // 16,777,216 B
    unsigned short* w1t   = (unsigned short*)(ws + 16777216);     //  2,097,152 B
    unsigned short* w2t   = (unsigned short*)(ws + 18874368);     //    524,288 B
    float*          gates = (float*)(ws + 19398656);              //  1,048,576 B  [16][B]
    unsigned short* h     = (unsigned short*)(ws + 20447232);     // 67,108,864 B
    // total: 87,556,096 B

    // dispatch 1: all prep + gates (x->bf16, W1^T, W2^T, gate softmax)
    prep_gates_kernel<<<dim3(1536), 256, 0, stream>>>(x, xb, W1, w1t, W2, w2t, Wg, bg, gates);

    // dispatch 2: layer 1 (verbatim r0): h[e] = relu(xb * w1t[e]^T + b1[e])
    gemm_relu_kernel<<<dim3(B_ / 128, H1_ / 128, E_), 256, 0, stream>>>(
        xb, 0, w1t, (size_t)H1_ * I_, b1, H1_, h, (size_t)B_ * H1_, I_, I_, I_, H1_);

    // dispatch 3: fused layer 2 + gated combine, split-n ring-3, 3 blocks/CU
    fused_l2_combine_kernel<<<dim3(B_ / 64), 512, 0, stream>>>(h, w2t, b2, gates, out);
}

// Round 11
// 159.431 us; speedup vs baseline: 1.1097x; 1.1097x over previous
//
#include <hip/hip_runtime.h>
#include <hip/hip_bf16.h>

#define B_  16384
#define I_  512
#define H1_ 256
#define H2_ 128
#define E_  8
#define T_  2

typedef __attribute__((ext_vector_type(8))) short short8;
typedef __attribute__((ext_vector_type(4))) float float4_t;

__device__ inline unsigned short f2bf(float f) {
    union { float f; unsigned u; } v; v.f = f;
    unsigned r = v.u + 0x7FFFu + ((v.u >> 16) & 1u);
    return (unsigned short)(r >> 16);
}

// async global->LDS, 16B per lane. LDS dest = wave-uniform base + lane*16.
__device__ inline void async_copy16(const unsigned short* g, unsigned short* l) {
    __builtin_amdgcn_global_load_lds(
        (const __attribute__((address_space(1))) void*)g,
        (__attribute__((address_space(3))) void*)l,
        16, 0, 0);
}

// ================= prep + gates megakernel (one dispatch) =================
// VERBATIM r9 (verified): 64-row gates blocks, float4 Wg staging, in-wave softmax.
__global__ void prep_gates_kernel(const float* __restrict__ x,
                                  unsigned short* __restrict__ xb,
                                  const float* __restrict__ W1,
                                  unsigned short* __restrict__ w1t,
                                  const float* __restrict__ W2,
                                  unsigned short* __restrict__ w2t,
                                  const float* __restrict__ Wg,
                                  const float* __restrict__ bg,
                                  float* __restrict__ gates) {
    __shared__ __align__(16) char smem[16 * 520 * 2 + 4 * 16 * 16 * 4];  // 20.6 KB
    int bid = blockIdx.x;
    int t = threadIdx.x;

    if (bid < 256) {
        unsigned short* wgtL = (unsigned short*)smem;          // [16][520] padded
#pragma unroll
        for (int j = 0; j < 8; ++j) {
            int idx4 = j * 256 + t;                 // 0..2047 float4s of Wg
            float4_t wv = ((const float4_t*)Wg)[idx4];
            int e0   = (idx4 & 1) * 4;
            int i    = (idx4 >> 1) & 511;
            int task = idx4 >> 10;
#pragma unroll
            for (int c = 0; c < 4; ++c)
                wgtL[(task * 8 + e0 + c) * 520 + i] = f2bf(wv[c]);
        }
        __syncthreads();

        int w = t >> 6, lane = t & 63;
        int col = lane & 15, quad = lane >> 4;
        int row = bid * 64 + w * 16 + col;          // this wave's A-row
        const float* xr = x + (size_t)row * I_ + quad * 8;
        unsigned short* xw = xb + (size_t)row * I_ + quad * 8;
        const unsigned short* bL = &wgtL[col * 520 + quad * 8];
        float4_t acc = {0.f, 0.f, 0.f, 0.f};
#pragma unroll
        for (int ks = 0; ks < 512; ks += 32) {
            float4_t xa = *(const float4_t*)(xr + ks);
            float4_t xc = *(const float4_t*)(xr + ks + 4);
            short8 a;
            a[0] = (short)f2bf(xa[0]); a[1] = (short)f2bf(xa[1]);
            a[2] = (short)f2bf(xa[2]); a[3] = (short)f2bf(xa[3]);
            a[4] = (short)f2bf(xc[0]); a[5] = (short)f2bf(xc[1]);
            a[6] = (short)f2bf(xc[2]); a[7] = (short)f2bf(xc[3]);
            *(short8*)(xw + ks) = a;
            short8 b = *(const short8*)(bL + ks);
            acc = __builtin_amdgcn_mfma_f32_16x16x32_bf16(a, b, acc, 0, 0, 0);
        }
        // per-lane: acc[p] = logits[local row quad*4+p][te=col]
        float g[4];
#pragma unroll
        for (int p = 0; p < 4; ++p) {
            float v = acc[p] + bg[col];
            float m = v;
            m = fmaxf(m, __shfl_xor(m, 1));
            m = fmaxf(m, __shfl_xor(m, 2));
            m = fmaxf(m, __shfl_xor(m, 4));
            float ev = __expf(v - m);
            float s = ev;
            s += __shfl_xor(s, 1);
            s += __shfl_xor(s, 2);
            s += __shfl_xor(s, 4);
            g[p] = ev / s;
        }
#pragma unroll
        for (int p = 0; p < 4; ++p)
            gates[(size_t)col * B_ + bid * 64 + w * 16 + quad * 4 + p] = g[p];
    } else {
        float (*tile)[33] = (float (*)[33])smem;
        const float* in; unsigned short* outp; int R, C, e, r0, c0;
        if (bid < 1280) {
            int tl = bid - 256;                // 8 e x 16 rblk x 8 cblk = 1024
            e = tl >> 7; int rem = tl & 127;
            R = I_; C = H1_;
            r0 = (rem >> 3) * 32; c0 = (rem & 7) * 32;
            in = W1; outp = w1t;
        } else {
            int tl = bid - 1280;               // 8 e x 8 rblk x 4 cblk = 256
            e = tl >> 5; int rem = tl & 31;
            R = H1_; C = H2_;
            r0 = (rem >> 2) * 32; c0 = (rem & 3) * 32;
            in = W2; outp = w2t;
        }
        const float* inp = in + (size_t)e * R * C;
        unsigned short* op = outp + (size_t)e * R * C;
        int tx = t & 31, ty = t >> 5;          // (32, 8)
#pragma unroll
        for (int j = 0; j < 32; j += 8)
            tile[ty + j][tx] = inp[(size_t)(r0 + ty + j) * C + c0 + tx];
        __syncthreads();
#pragma unroll
        for (int j = 0; j < 32; j += 8)
            op[(size_t)(c0 + ty + j) * R + r0 + tx] = f2bf(tile[tx][ty + j]);
    }
}

// ---------------- layer 1 grouped GEMM: h[e] = relu(xb * w1t[e]^T + b1[e]) bf16 ----------------
// VERBATIM r0 (proven ~49 us): 128x128 tile, 256 threads, 4 blocks/CU,
// LDS 34816 B (As|Bs aliased by padded C-tile in the epilogue).
__global__ void gemm_relu_kernel(const unsigned short* __restrict__ A, size_t aSE,
                                 const unsigned short* __restrict__ Bt, size_t bSE,
                                 const float* __restrict__ bias, int biasSE,
                                 unsigned short* __restrict__ C, size_t cSE,
                                 int K, int lda, int ldb, int ldc) {
    __shared__ unsigned short smem[128 * 136];   // 34 KB: As|Bs, aliased by padded C-tile
    unsigned short* As = smem;                    // 128*64
    unsigned short* Bs = smem + 128 * 64;         // 128*64
    int e = blockIdx.z;
    const unsigned short* Ae = A + (size_t)e * aSE;
    const unsigned short* Be = Bt + (size_t)e * bSE;
    const float* biasE = bias + (size_t)e * biasSE;
    unsigned short* Ce = C + (size_t)e * cSE;
    int m0 = blockIdx.x * 128, n0 = blockIdx.y * 128;
    int t = threadIdx.x, w = t >> 6, lane = t & 63;
    int col = lane & 15, quad = lane >> 4;
    int wm = (w & 1) * 64, wn = (w >> 1) * 64;

    float4_t acc[4][4];
#pragma unroll
    for (int mi = 0; mi < 4; ++mi)
#pragma unroll
        for (int ni = 0; ni < 4; ++ni)
            acc[mi][ni] = (float4_t){0.f, 0.f, 0.f, 0.f};

    int rT = t >> 3;
    int gk = (((t & 7) ^ (rT & 7))) * 8;
    const unsigned short* aG = Ae + (size_t)(m0 + rT) * lda + gk;
    const unsigned short* bG = Be + (size_t)(n0 + rT) * ldb + gk;
    unsigned short* aL = As + (size_t)w * 64 * 8;
    unsigned short* bL = Bs + (size_t)w * 64 * 8;

    for (int k0 = 0; k0 < K; k0 += 64) {
#pragma unroll
        for (int j = 0; j < 4; ++j) {
            async_copy16(aG + (size_t)j * 32 * lda + k0, aL + j * 2048);
            async_copy16(bG + (size_t)j * 32 * ldb + k0, bL + j * 2048);
        }
        __syncthreads();
#pragma unroll
        for (int kk = 0; kk < 64; kk += 32) {
            int q = (kk >> 3) + quad;
            short8 af[4], bf[4];
#pragma unroll
            for (int mi = 0; mi < 4; ++mi) {
                int r = wm + mi * 16 + col;
                af[mi] = *(const short8*)&As[r * 64 + ((q ^ (r & 7)) * 8)];
            }
#pragma unroll
            for (int ni = 0; ni < 4; ++ni) {
                int r = wn + ni * 16 + col;
                bf[ni] = *(const short8*)&Bs[r * 64 + ((q ^ (r & 7)) * 8)];
            }
#pragma unroll
            for (int mi = 0; mi < 4; ++mi)
#pragma unroll
                for (int ni = 0; ni < 4; ++ni)
                    acc[mi][ni] = __builtin_amdgcn_mfma_f32_16x16x32_bf16(af[mi], bf[ni], acc[mi][ni], 0, 0, 0);
        }
        __syncthreads();
    }
    // after final barrier all LDS reads are done -> safe to alias as padded C-tile
    unsigned short* Ct = smem;   // 128 rows x stride 136
#pragma unroll
    for (int ni = 0; ni < 4; ++ni) {
        int c = wn + ni * 16 + col;
        float bv = biasE[n0 + c];
#pragma unroll
        for (int mi = 0; mi < 4; ++mi) {
            int rbase = wm + mi * 16 + quad * 4;
#pragma unroll
            for (int p = 0; p < 4; ++p) {
                float v = acc[mi][ni][p] + bv;
                v = v > 0.f ? v : 0.f;
                Ct[(rbase + p) * 136 + c] = f2bf(v);
            }
        }
    }
    __syncthreads();
    int rr = t >> 4, sl = t & 15;
#pragma unroll
    for (int pass = 0; pass < 8; ++pass) {
        int row = pass * 16 + rr;
        short8 vv = *(const short8*)&Ct[row * 136 + sl * 8];
        *(short8*)&Ce[(size_t)(m0 + row) * ldc + n0 + sl * 8] = vv;
    }
}

// ---------------- fused layer2 + gated combine: ring-3, depth-1 prefetch ----------------
// VERBATIM r4 (verified best of 4 variants, ~24.7 us). 64 rows x full H2 per
// block, grid 256, 76 KB -> 2 blocks/CU. Per chunk cid:
//   [stage(cid+1) -> slot (cid+1)%3] [vmcnt(3)] [s_barrier] [compute slot cid%3]
// Race-free (R=3 >= D+2 with D=1). h is L3-resident (r10 FETCH evidence), so
// the kernel is latency/barrier-bound, not BW-bound; 8-MFMA-per-wave chunks
// are the measured sweet spot (split-n halving regressed 2x).
__global__ __launch_bounds__(512, 4)
void fused_l2_combine_kernel(const unsigned short* __restrict__ h,
                             const unsigned short* __restrict__ w2t,
                             const float* __restrict__ b2,
                             const float* __restrict__ gates,
                             float* __restrict__ out) {
    __shared__ __align__(16) unsigned short ring[36864];   // 72 KB: A[3][4096] | B[3][8192]
    __shared__ float gL[16][64];                           //  4 KB

    unsigned short* Aslot = ring;
    unsigned short* Bslot = ring + 12288;

    int b0 = blockIdx.x * 64;
    int t = threadIdx.x, w = t >> 6, lane = t & 63;
    int col = lane & 15, quad = lane >> 4;
    int wm = (w & 1) * 32, wn = (w >> 1) * 32;

    if (t < 256) {
        int te = t >> 4, r4 = (t & 15) * 4;
        *(float4_t*)&gL[te][r4] = *(const float4_t*)&gates[(size_t)te * B_ + b0 + r4];
    }

    int rowA = t >> 3;
    int csw  = ((t & 7) ^ (rowA & 7)) * 8;
    int ldsw = w * 512;

    float4_t tw0[2][2], tw1[2][2];
#pragma unroll
    for (int mi = 0; mi < 2; ++mi)
#pragma unroll
        for (int ni = 0; ni < 2; ++ni) {
            tw0[mi][ni] = (float4_t){0.f, 0.f, 0.f, 0.f};
            tw1[mi][ni] = (float4_t){0.f, 0.f, 0.f, 0.f};
        }

    auto stage = [&](int cid, int slot) {
        int ee = cid >> 2, kc = cid & 3;
        const unsigned short* hE = h + ((size_t)ee * B_ + b0 + rowA) * H1_ + kc * 64 + csw;
        async_copy16(hE, Aslot + slot * 4096 + ldsw);
        const unsigned short* wE = w2t + ((size_t)ee * H2_ + rowA) * H1_ + kc * 64 + csw;
        async_copy16(wE, Bslot + slot * 8192 + ldsw);
        async_copy16(wE + (size_t)64 * H1_, Bslot + slot * 8192 + 4096 + ldsw);
    };

    stage(0, 0);

    float4_t acc[2][2];
    int rd = 0, wr = 1;
#pragma unroll 1
    for (int cid = 0; cid < 32; ++cid) {
        if (cid < 31) {
            stage(cid + 1, wr);
            asm volatile("s_waitcnt vmcnt(3)" ::: "memory");
        } else {
            asm volatile("s_waitcnt vmcnt(0)" ::: "memory");
        }
        asm volatile("s_barrier" ::: "memory");

        if ((cid & 3) == 0) {
#pragma unroll
            for (int mi = 0; mi < 2; ++mi)
#pragma unroll
                for (int ni = 0; ni < 2; ++ni)
                    acc[mi][ni] = (float4_t){0.f, 0.f, 0.f, 0.f};
        }
        const unsigned short* Ac = Aslot + rd * 4096;
        const unsigned short* Bc = Bslot + rd * 8192;
#pragma unroll
        for (int kq = 0; kq < 2; ++kq) {
            int q = kq * 4 + quad;
            short8 af[2], bfv[2];
#pragma unroll
            for (int mi = 0; mi < 2; ++mi) {
                int r = wm + mi * 16 + col;
                af[mi] = *(const short8*)&Ac[r * 64 + ((q ^ (r & 7)) << 3)];
            }
#pragma unroll
            for (int ni = 0; ni < 2; ++ni) {
                int n = wn + ni * 16 + col;
                bfv[ni] = *(const short8*)&Bc[n * 64 + ((q ^ (n & 7)) << 3)];
            }
            __builtin_amdgcn_s_setprio(1);
#pragma unroll
            for (int mi = 0; mi < 2; ++mi)
#pragma unroll
                for (int ni = 0; ni < 2; ++ni)
                    acc[mi][ni] = __builtin_amdgcn_mfma_f32_16x16x32_bf16(
                        af[mi], bfv[ni], acc[mi][ni], 0, 0, 0);
            __builtin_amdgcn_s_setprio(0);
        }

        if ((cid & 3) == 3) {
            int ee = cid >> 2;
#pragma unroll
            for (int ni = 0; ni < 2; ++ni) {
                float bv = b2[ee * H2_ + wn + ni * 16 + col];
#pragma unroll
                for (int mi = 0; mi < 2; ++mi) {
#pragma unroll
                    for (int p = 0; p < 4; ++p) {
                        int rloc = wm + mi * 16 + quad * 4 + p;
                        float v = acc[mi][ni][p] + bv;
                        v = v > 0.f ? v : 0.f;
                        tw0[mi][ni][p] += gL[ee][rloc] * v;
                        tw1[mi][ni][p] += gL[8 + ee][rloc] * v;
                    }
                }
            }
        }
        rd = (rd == 2) ? 0 : rd + 1;
        wr = (wr == 2) ? 0 : wr + 1;
    }

#pragma unroll
    for (int mi = 0; mi < 2; ++mi) {
#pragma unroll
        for (int ni = 0; ni < 2; ++ni) {
            int n = wn + ni * 16 + col;
#pragma unroll
            for (int p = 0; p < 4; ++p) {
                int r = b0 + wm + mi * 16 + quad * 4 + p;
                out[(size_t)r * H2_ + n] = tw0[mi][ni][p];
                out[(size_t)B_ * H2_ + (size_t)r * H2_ + n] = tw1[mi][ni][p];
            }
        }
    }
}

extern "C" void kernel_launch(void* const* d_in, const int* in_sizes, int n_in,
                              void* d_out, int out_size, void* d_ws, size_t ws_size,
                              hipStream_t stream) {
    const float* x  = (const float*)d_in[0];
    const float* W1 = (const float*)d_in[1];
    const float* b1 = (const float*)d_in[2];
    const float* W2 = (const float*)d_in[3];
    const float* b2 = (const float*)d_in[4];
    const float* Wg = (const float*)d_in[5];
    const float* bg = (const float*)d_in[6];
    float* out = (float*)d_out;

    char* ws = (char*)d_ws;
    unsigned short* xb    = (unsigned short*)(ws);                // 16,777,216 B
    unsigned short* w1t   = (unsigned short*)(ws + 16777216);     //  2,097,152 B
    unsigned short* w2t   = (unsigned short*)(ws + 18874368);     //    524,288 B
    float*          gates = (float*)(ws + 19398656);              //  1,048,576 B  [16][B]
    unsigned short* h     = (unsigned short*)(ws + 20447232);     // 67,108,864 B
    // total: 87,556,096 B

    // dispatch 1: all prep + gates (x->bf16, W1^T, W2^T, gate softmax)
    prep_gates_kernel<<<dim3(1536), 256, 0, stream>>>(x, xb, W1, w1t, W2, w2t, Wg, bg, gates);

    // dispatch 2: layer 1 (verbatim r0): h[e] = relu(xb * w1t[e]^T + b1[e])
    gemm_relu_kernel<<<dim3(B_ / 128, H1_ / 128, E_), 256, 0, stream>>>(
        xb, 0, w1t, (size_t)H1_ * I_, b1, H1_, h, (size_t)B_ * H1_, I_, I_, I_, H1_);

    // dispatch 3: fused layer 2 + gated combine, ring-3 depth-1, 2 blocks/CU
    fused_l2_combine_kernel<<<dim3(B_ / 64), 512, 0, stream>>>(h, w2t, b2, gates, out);
}